// Round 6
// baseline (195.688 us; speedup 1.0000x reference)
//
#include <hip/hip_runtime.h>

#define IMG_W 1024
#define IMG_H 1024
#define RPW   4     // output rows per wave-strip

typedef float floatx4 __attribute__((ext_vector_type(4)));

__global__ __launch_bounds__(256) void dir_rhs_kernel(
    const float* __restrict__ u,
    const float* __restrict__ f,
    const float* __restrict__ wt,
    float* __restrict__ out)
{
    const int tid  = threadIdx.x;
    const int lane = tid & 63;
    const int wv   = tid >> 6;

    // XCD swizzle: blocks dispatch round-robin over 8 XCDs; give each XCD a
    // contiguous run of strip-groups so halo rows reuse the same XCD's L2.
    const int phys = blockIdx.x;               // 0..1023
    const int lblk = ((phys & 7) << 7) + (phys >> 3);
    const int strip = (lblk << 2) + wv;        // 0..4095
    const int b   = strip >> 8;                // 256 strips per image
    const int r0  = (strip & 255) * RPW;
    const int c0  = lane << 4;                 // 16 contiguous cols per lane
    const size_t img = (size_t)b << 20;

    const float* ub = u + img + c0;
    const float* fb = f + img + c0;
    float*       ob = out + img + c0;

    const float w00 = wt[0], w01 = wt[1], w02 = wt[2];
    const float w10 = wt[3], w11 = wt[4], w12 = wt[5];
    const float w20 = wt[6], w21 = wt[7], w22 = wt[8];
    const float cof = (float)(-(1.0 / 1023.0) * (1.0 / 1023.0) / 4.0);

    // raw load of a v-row (zeros outside interior rows); no shfl here so the
    // prefetch never forces an early waitcnt
    auto load_v = [&](int g, float* a) {
        if (g >= 1 && g <= IMG_H - 2) {
            const floatx4* p = (const floatx4*)(ub + (size_t)g * IMG_W);
            floatx4 q0 = p[0], q1 = p[1], q2 = p[2], q3 = p[3];
            a[0]=q0.x; a[1]=q0.y; a[2]=q0.z; a[3]=q0.w;
            a[4]=q1.x; a[5]=q1.y; a[6]=q1.z; a[7]=q1.w;
            a[8]=q2.x; a[9]=q2.y; a[10]=q2.z; a[11]=q2.w;
            a[12]=q3.x; a[13]=q3.y; a[14]=q3.z; a[15]=q3.w;
        } else {
            #pragma unroll
            for (int e = 0; e < 16; e++) a[e] = 0.f;
        }
    };
    auto load_f = [&](int g, float* a) {
        const floatx4* p = (const floatx4*)(fb + (size_t)g * IMG_W);
        floatx4 q0 = p[0], q1 = p[1], q2 = p[2], q3 = p[3];
        a[0]=q0.x; a[1]=q0.y; a[2]=q0.z; a[3]=q0.w;
        a[4]=q1.x; a[5]=q1.y; a[6]=q1.z; a[7]=q1.w;
        a[8]=q2.x; a[9]=q2.y; a[10]=q2.z; a[11]=q2.w;
        a[12]=q3.x; a[13]=q3.y; a[14]=q3.z; a[15]=q3.w;
    };
    // boundary-column zeroing + halo exchange (consumes the loads)
    auto finalize = [&](float* a, float& lh, float& rh) {
        if (lane == 0)  a[0]  = 0.f;   // col 0 is boundary in v
        if (lane == 63) a[15] = 0.f;   // col 1023 is boundary in v
        lh = __shfl_up(a[15], 1, 64);  // col c0-1 from left lane
        rh = __shfl_down(a[0], 1, 64); // col c0+16 from right lane
    };

    float vm[16], vc[16], vp[16], vn[16], fr[16], fn[16];
    float lhm, rhm, lhc, rhc, lhp, rhp;

    load_v(r0 - 1, vm);
    load_v(r0,     vc);
    load_v(r0 + 1, vp);
    load_f(r0,     fr);
    finalize(vm, lhm, rhm);
    finalize(vc, lhc, rhc);

    #pragma unroll
    for (int k = 0; k < RPW; k++) {
        if (k < RPW - 1) {              // prefetch two rows ahead
            load_v(r0 + k + 2, vn);
            load_f(r0 + k + 1, fn);
        }
        finalize(vp, lhp, rhp);         // waits only on vp's 4 loads

        const int g = r0 + k;
        float res[16];
        #pragma unroll
        for (int e = 0; e < 16; e++) {
            const float lm = (e == 0) ? lhm : vm[e - 1];
            const float rm = (e == 15) ? rhm : vm[e + 1];
            const float lc = (e == 0) ? lhc : vc[e - 1];
            const float rc = (e == 15) ? rhc : vc[e + 1];
            const float lp = (e == 0) ? lhp : vp[e - 1];
            const float rp = (e == 15) ? rhp : vp[e + 1];
            float acc = cof * fr[e];
            acc += w00 * lm + w01 * vm[e] + w02 * rm;
            acc += w10 * lc + w11 * vc[e] + w12 * rc;
            acc += w20 * lp + w21 * vp[e] + w22 * rp;
            res[e] = acc;
        }
        if (g == 0 || g == IMG_H - 1) {
            #pragma unroll
            for (int e = 0; e < 16; e++) res[e] = 0.f;   // boundary rows
        }
        if (lane == 0)  res[0]  = 0.f;  // boundary cols
        if (lane == 63) res[15] = 0.f;

        floatx4* o4 = (floatx4*)(ob + (size_t)g * IMG_W);
        floatx4 s0 = { res[0],  res[1],  res[2],  res[3]  };
        floatx4 s1 = { res[4],  res[5],  res[6],  res[7]  };
        floatx4 s2 = { res[8],  res[9],  res[10], res[11] };
        floatx4 s3 = { res[12], res[13], res[14], res[15] };
        o4[0] = s0; o4[1] = s1; o4[2] = s2; o4[3] = s3;

        if (k < RPW - 1) {              // rotate rolling window
            #pragma unroll
            for (int e = 0; e < 16; e++) { vm[e] = vc[e]; vc[e] = vp[e]; vp[e] = vn[e]; fr[e] = fn[e]; }
            lhm = lhc; rhm = rhc; lhc = lhp; rhc = rhp;
        }
    }
}

extern "C" void kernel_launch(void* const* d_in, const int* in_sizes, int n_in,
                              void* d_out, int out_size, void* d_ws, size_t ws_size,
                              hipStream_t stream) {
    const float* u  = (const float*)d_in[0];
    const float* f  = (const float*)d_in[1];
    const float* wt = (const float*)d_in[2];
    float* out = (float*)d_out;

    const int B = 16;
    // 4096 wave-strips (16 images x 256 strips), 4 waves per 256-thread block
    dim3 grid(B * (IMG_H / RPW) / 4);
    dim3 block(256);
    dir_rhs_kernel<<<grid, block, 0, stream>>>(u, f, wt, out);
}